// Round 7
// baseline (217.525 us; speedup 1.0000x reference)
//
#include <hip/hip_runtime.h>
#include <hip/hip_bf16.h>
#include <math.h>

#define SEQ 4096
#define EMB 1024
#define NH  16
#define DK  64

typedef __attribute__((ext_vector_type(8))) unsigned short us8;
typedef __attribute__((ext_vector_type(8))) short         s8;
typedef __attribute__((ext_vector_type(4))) unsigned short us4;
typedef __attribute__((ext_vector_type(4))) float          f4;

static __device__ __forceinline__ unsigned short f2bf(float f) {
    union { float f; unsigned u; } v; v.f = f;
    unsigned r = v.u + 0x7FFF + ((v.u >> 16) & 1);
    return (unsigned short)(r >> 16);
}

__device__ __forceinline__ void gl2lds16(const void* g, void* l) {
    __builtin_amdgcn_global_load_lds((const __attribute__((address_space(1))) void*)g,
                                     (__attribute__((address_space(3))) void*)l, 16, 0, 0);
}

// pack two fp32 -> one dword of two truncated bf16 (hi = a, lo = b): one v_perm_b32
__device__ __forceinline__ int pkbf(float a, float b) {
    return (int)__builtin_amdgcn_perm(__float_as_uint(a), __float_as_uint(b), 0x07060302u);
}

// ---------------- fp32 -> bf16 convert, all 5 tensors in one launch ----------------
__global__ void cvt_all(const float* __restrict__ x,
                        const float* __restrict__ w0, const float* __restrict__ w1,
                        const float* __restrict__ w2, const float* __restrict__ w3,
                        unsigned short* __restrict__ xo,
                        unsigned short* __restrict__ o0, unsigned short* __restrict__ o1,
                        unsigned short* __restrict__ o2, unsigned short* __restrict__ o3) {
    const int idx = blockIdx.x * 256 + threadIdx.x;
    const float* in;
    unsigned short* out;
    int off;
    if (idx < (1 << 20)) { in = x; out = xo; off = idx; }
    else {
        const int t = idx - (1 << 20);
        const int w = t >> 18;
        off = t & ((1 << 18) - 1);
        in  = w == 0 ? w0 : (w == 1 ? w1 : (w == 2 ? w2 : w3));
        out = w == 0 ? o0 : (w == 1 ? o1 : (w == 2 ? o2 : o3));
    }
    const float4 v = ((const float4*)in)[off];
    us4 o;
    o[0] = f2bf(v.x); o[1] = f2bf(v.y); o[2] = f2bf(v.z); o[3] = f2bf(v.w);
    ((us4*)out)[off] = o;
}

// ---------------- fused QKV projection GEMM, 128x128 tile ----------------
// Regions 0/1 (Q,K) use SWAPPED mfma operands: mfma(bf, af) puts m on the lane dim and
// 4 consecutive n in registers -> us4 stores (8B/lane) + float4 bias. Region 2 (V)
// keeps the original order (n on lanes, needed for the transposed Vt store) and merges
// tm-pairs into us8 (16B/lane) under the k-perm layout.
__global__ __launch_bounds__(256) void qkv_gemm(
    const unsigned short* __restrict__ X,
    const unsigned short* __restrict__ Wq, const unsigned short* __restrict__ Wk,
    const unsigned short* __restrict__ Wv,
    const float* __restrict__ bq, const float* __restrict__ bk, const float* __restrict__ bv,
    unsigned short* __restrict__ Qo, unsigned short* __restrict__ Ko, unsigned short* __restrict__ Vto)
{
    __shared__ unsigned short As[128 * 64];
    __shared__ unsigned short Bs[128 * 64];

    // XCD-bijective swizzle: 768 blocks = 8 XCDs x 96
    const int flat = blockIdx.y * 32 + blockIdx.x;
    const int wg   = (flat & 7) * 96 + (flat >> 3);
    const int bxi  = wg & 31;
    const int byi  = wg >> 5;

    const int region = byi >> 3;
    const unsigned short* W   = region == 0 ? Wq : (region == 1 ? Wk : Wv);
    const float*         bias = region == 0 ? bq : (region == 1 ? bk : bv);
    const float scale = region == 0 ? 0.18033688011112042f : 1.0f;   // 0.125 * log2(e)

    const int tid  = threadIdx.x;
    const int wave = tid >> 6;
    const int lane = tid & 63;
    const int quad = lane >> 4;
    const int l16  = lane & 15;
    const int wm   = (wave >> 1) * 64;
    const int wn   = (wave & 1) * 64;
    const int bm   = bxi * 128;
    const int bn   = (byi & 7) * 128;

    f4 acc[4][4];
#pragma unroll
    for (int a = 0; a < 4; ++a)
#pragma unroll
        for (int b = 0; b < 4; ++b) acc[a][b] = (f4){0, 0, 0, 0};

    const int rsub = lane >> 3;
    const int gc   = ((lane & 7) ^ rsub) * 8;
    const int swz  = l16 & 7;

    for (int k0 = 0; k0 < EMB; k0 += 64) {
        __syncthreads();
#pragma unroll
        for (int i = 0; i < 4; ++i) {
            const int cb = i * 4 + wave;
            const int r  = cb * 8 + rsub;
            gl2lds16(X + (size_t)(bm + r) * EMB + k0 + gc, &As[cb * 512]);
            gl2lds16(W + (size_t)(bn + r) * EMB + k0 + gc, &Bs[cb * 512]);
        }
        __syncthreads();
        if (region != 2) {          // Q,K: swapped operands (m on lanes, n in regs)
#pragma unroll
            for (int kc = 0; kc < 2; ++kc) {
                s8 af[4], bf[4];
#pragma unroll
                for (int t = 0; t < 4; ++t) {
                    const int seg = (kc * 4 + quad) ^ swz;
                    af[t] = *(const s8*)&As[(wm + t * 16 + l16) * 64 + seg * 8];
                    bf[t] = *(const s8*)&Bs[(wn + t * 16 + l16) * 64 + seg * 8];
                }
#pragma unroll
                for (int tm = 0; tm < 4; ++tm)
#pragma unroll
                    for (int tn = 0; tn < 4; ++tn)
                        acc[tm][tn] = __builtin_amdgcn_mfma_f32_16x16x32_bf16(bf[tn], af[tm], acc[tm][tn], 0, 0, 0);
            }
        } else {                    // V: original order (n on lanes) for Vt store
#pragma unroll
            for (int kc = 0; kc < 2; ++kc) {
                s8 af[4], bf[4];
#pragma unroll
                for (int t = 0; t < 4; ++t) {
                    const int seg = (kc * 4 + quad) ^ swz;
                    af[t] = *(const s8*)&As[(wm + t * 16 + l16) * 64 + seg * 8];
                    bf[t] = *(const s8*)&Bs[(wn + t * 16 + l16) * 64 + seg * 8];
                }
#pragma unroll
                for (int tm = 0; tm < 4; ++tm)
#pragma unroll
                    for (int tn = 0; tn < 4; ++tn)
                        acc[tm][tn] = __builtin_amdgcn_mfma_f32_16x16x32_bf16(af[tm], bf[tn], acc[tm][tn], 0, 0, 0);
            }
        }
    }

    if (region == 2) {
        // transposed + k-permuted store into Vt [EMB][SEQ]; us8 merges tm pairs
#pragma unroll
        for (int tn = 0; tn < 4; ++tn) {
            const int n = bn + wn + tn * 16 + l16;          // output d-column (per lane)
            const float bv2 = bias[n];
            unsigned short* dst = Vto + (size_t)n * SEQ + bm + (wm & 64) + quad * 8;
            us8 ov;
#pragma unroll
            for (int rr = 0; rr < 4; ++rr) {
                ov[rr]     = f2bf(acc[0][tn][rr] + bv2);
                ov[4 + rr] = f2bf(acc[1][tn][rr] + bv2);
            }
            *(us8*)dst = ov;
#pragma unroll
            for (int rr = 0; rr < 4; ++rr) {
                ov[rr]     = f2bf(acc[2][tn][rr] + bv2);
                ov[4 + rr] = f2bf(acc[3][tn][rr] + bv2);
            }
            *(us8*)(dst + 32) = ov;
        }
    } else {
        unsigned short* out = region == 0 ? Qo : Ko;
#pragma unroll
        for (int tn = 0; tn < 4; ++tn) {
            const int n4 = bn + wn + tn * 16 + quad * 4;    // 4 consecutive n in regs
            const f4 bv4 = *(const f4*)&bias[n4];
#pragma unroll
            for (int tm = 0; tm < 4; ++tm) {
                const int m = bm + wm + tm * 16 + l16;      // m per lane
                us4 ov;
#pragma unroll
                for (int rr = 0; rr < 4; ++rr) ov[rr] = f2bf((acc[tm][tn][rr] + bv4[rr]) * scale);
                *(us4*)&out[(size_t)m * EMB + n4] = ov;
            }
        }
    }
}

// ---------------- output projection GEMM, 128x64 tile, fp32 out ----------------
// Swapped mfma operands: m on lanes, 4 consecutive n in regs -> float4 stores.
__global__ __launch_bounds__(256) void gemm_op(
    const unsigned short* __restrict__ A, const unsigned short* __restrict__ B,
    const float* __restrict__ bias, float* __restrict__ C)
{
    __shared__ unsigned short As[128 * 64];
    __shared__ unsigned short Bs[64 * 64];

    // XCD-bijective swizzle: 512 blocks = 8 x 64
    const int flat = blockIdx.y * 32 + blockIdx.x;
    const int wg   = (flat & 7) * 64 + (flat >> 3);
    const int bxi  = wg & 31;
    const int byi  = wg >> 5;

    const int tid  = threadIdx.x;
    const int wave = tid >> 6;
    const int lane = tid & 63;
    const int quad = lane >> 4;
    const int l16  = lane & 15;
    const int wm   = (wave >> 1) * 64;
    const int wn   = (wave & 1) * 32;
    const int bm   = bxi * 128;
    const int bn   = byi * 64;

    f4 acc[4][2];
#pragma unroll
    for (int a = 0; a < 4; ++a) { acc[a][0] = (f4){0,0,0,0}; acc[a][1] = (f4){0,0,0,0}; }

    const int rsub = lane >> 3;
    const int gc   = ((lane & 7) ^ rsub) * 8;
    const int swz  = l16 & 7;

    for (int k0 = 0; k0 < EMB; k0 += 64) {
        __syncthreads();
#pragma unroll
        for (int i = 0; i < 6; ++i) {
            const int cb = i * 4 + wave;
            if (cb < 16) {
                gl2lds16(A + (size_t)(bm + cb * 8 + rsub) * EMB + k0 + gc, &As[cb * 512]);
            } else {
                const int c2 = cb - 16;
                gl2lds16(B + (size_t)(bn + c2 * 8 + rsub) * EMB + k0 + gc, &Bs[c2 * 512]);
            }
        }
        __syncthreads();
#pragma unroll
        for (int kc = 0; kc < 2; ++kc) {
            const int seg = (kc * 4 + quad) ^ swz;
            s8 af[4], bf[2];
#pragma unroll
            for (int t = 0; t < 4; ++t)
                af[t] = *(const s8*)&As[(wm + t * 16 + l16) * 64 + seg * 8];
#pragma unroll
            for (int t = 0; t < 2; ++t)
                bf[t] = *(const s8*)&Bs[(wn + t * 16 + l16) * 64 + seg * 8];
#pragma unroll
            for (int tm = 0; tm < 4; ++tm)
#pragma unroll
                for (int tn = 0; tn < 2; ++tn)
                    acc[tm][tn] = __builtin_amdgcn_mfma_f32_16x16x32_bf16(bf[tn], af[tm], acc[tm][tn], 0, 0, 0);
        }
    }

#pragma unroll
    for (int tn = 0; tn < 2; ++tn) {
        const int n4 = bn + wn + tn * 16 + quad * 4;        // 4 consecutive n in regs
        const f4 bv4 = *(const f4*)&bias[n4];
#pragma unroll
        for (int tm = 0; tm < 4; ++tm) {
            const int m = bm + wm + tm * 16 + l16;          // m per lane
            f4 v = acc[tm][tn] + bv4;
            *(f4*)&C[(size_t)m * EMB + n4] = v;             // 16B store
        }
    }
}

// ---------------- Flash attention (causal): 64q/wave, parity waves, 4-wave block ------
// Q,K: bf16 [SEQ][EMB] (Q pre-scaled 0.125*log2e). Vt: bf16 [EMB][SEQ], k-permuted cols.
// Block = 256 thr / 4 waves, grid (NH,32), u = y<16 ? y : 47-y, tiles {63-u, u} (the
// round-1 pairing: uniform block durations, no tail). Waves = {tile} x {j parity}; each
// wave now covers ALL 64 q-rows of its tile (4 qn subtiles of 16 rows). K/V fragment
// reads are q-independent, so one 16-read set feeds 4 qn -> 64 MFMA per chunk (1:4
// read:MFMA, 2x round-1) -> CU DS-pipe load HALVES (1536 -> ~768 cyc/iter), which the
// pipe model says was the top consumer. VALU (~750/SIMD, exp2-dominated) now co-critical.
// VGPR ~185 (o 64 + s 64 + qf 32), launch_bounds(256,2) caps at 256 -> 2 blocks/CU,
// 8 waves/CU. LDS: K,V XOR-swizzled [64][64] tiles via gl2lds pre-swizzled src (2 passes
// of 32 rows, 256 thr). Parity partials merge through dead Ks/Vs at epilogue.
// Fixed-max softmax, exp2 domain, zero-shfl PV, setprio on MFMA clusters (T5).
__global__ __launch_bounds__(256, 2) void attn_kernel(
    const unsigned short* __restrict__ Qg, const unsigned short* __restrict__ Kg,
    const unsigned short* __restrict__ Vtg, unsigned short* __restrict__ Og)
{
    __shared__ unsigned short Ks[2][2][64][64];   // [buf][parity][row][col^swz] 32KB
    __shared__ unsigned short Vs[2][2][64][64];   //                              32KB

    const int tid  = threadIdx.x;
    const int wave = tid >> 6;                    // 0..3
    const int lane = tid & 63;
    const int quad = lane >> 4;
    const int l16  = lane & 15;
    const int h    = blockIdx.x;
    const int y    = blockIdx.y;
    const int u    = (y < 16) ? y : 47 - y;
    const int jmax = 63 - u;                      // tile-A diagonal, >= 32
    const int par  = wave & 1;                    // j parity this wave computes
    const bool isA = wave < 2;
    const int tileMine = isA ? jmax : u;
    const int jmine    = tileMine;
    const int colbase  = h * DK;
    const int q0       = tileMine * 64 + l16;     // qn row = q0 + 16*qn

    // Q B-frags qf[qn][kc]: B[n=q][k=kc*32+quad*8+j]
    s8 qf[4][2];
#pragma unroll
    for (int qn = 0; qn < 4; ++qn) {
        const unsigned short* q = Qg + (size_t)(q0 + 16 * qn) * EMB + colbase + quad * 8;
        qf[qn][0] = *(const s8*)(q);
        qf[qn][1] = *(const s8*)(q + 32);
    }

    // swizzled LDS read offsets (shorts)
    const int xr    = (l16 & 7) << 4;
    const int coff0 = ((quad * 16) ^ xr) >> 1;
    const int coff1 = ((64 + quad * 16) ^ xr) >> 1;

    // staging: 256 thr cover rows 0..31 (pass 0) and 32..63 (pass 1), 16B chunks;
    // linear LDS dest (wave base + lane*16), global source pre-swizzled.
    // (srow+32)&7 == srow&7, so the same scol works for both passes.
    const int srow = tid >> 3;                    // 0..31
    const int scol = (((tid & 7) * 16) ^ ((srow & 7) << 4)) >> 1;
    const unsigned short* ksrc = Kg  + (size_t)srow * EMB + colbase + scol;
    const unsigned short* vsrc = Vtg + (size_t)(colbase + srow) * SEQ + scol;
    const int ldo = wave * 512;                   // shorts: 1KB per wave per pass

#define STAGE_PAIR(buf, sub, jt) do {                                              \
        unsigned short* kD = &Ks[buf][sub][0][0];                                  \
        unsigned short* vD = &Vs[buf][sub][0][0];                                  \
        gl2lds16(ksrc + (size_t)(jt) * 64 * EMB,        kD + ldo);                 \
        gl2lds16(ksrc + (size_t)((jt) * 64 + 32) * EMB, kD + 2048 + ldo);          \
        gl2lds16(vsrc + (jt) * 64,                      vD + ldo);                 \
        gl2lds16(vsrc + (size_t)32 * SEQ + (jt) * 64,   vD + 2048 + ldo);          \
    } while (0)

    const int imax = jmax >> 1;                   // pair index range 0..imax

    // stage pair 0 (j=0,1; j=1 exists since jmax >= 32)
    STAGE_PAIR(0, 0, 0);
    STAGE_PAIR(0, 1, 1);

    float l[4] = {0.f, 0.f, 0.f, 0.f};
    f4 o[4][4];
#pragma unroll
    for (int qn = 0; qn < 4; ++qn)
#pragma unroll
        for (int t = 0; t < 4; ++t) o[qn][t] = (f4){0, 0, 0, 0};

    for (int i = 0; i <= imax; ++i) {
        __syncthreads();                          // pair i staged; buffers safe to swap
        const int cur = i & 1;
        if (i < imax) {                           // issue pair i+1 (drained by next barrier)
            const int nxt = cur ^ 1;
            const int je  = 2 * (i + 1);
            STAGE_PAIR(nxt, 0, je);
            const int jo = je + 1;
            if (jo <= jmax) STAGE_PAIR(nxt, 1, jo);   // block-uniform guard
        }

        const int j = 2 * i + par;
        if (j <= jmine) {
            const unsigned short* KsP = &Ks[cur][par][0][0];
            const unsigned short* VsP = &Vs[cur][par][0][0];

            // S^T[k][q] = K . Q^T; one K fragment pair feeds 4 q-subtiles
            f4 s[4][4];
#pragma unroll
            for (int qn = 0; qn < 4; ++qn)
#pragma unroll
                for (int t = 0; t < 4; ++t) s[qn][t] = (f4){0, 0, 0, 0};

            __builtin_amdgcn_s_setprio(1);
#pragma unroll
            for (int t = 0; t < 4; ++t) {
                const int rbase = (t * 16 + l16) * 64;
                s8 kv0 = *(const s8*)&KsP[rbase + coff0];
                s8 kv1 = *(const s8*)&KsP[rbase + coff1];
#pragma unroll
                for (int qn = 0; qn < 4; ++qn) {
                    s[qn][t] = __builtin_amdgcn_mfma_f32_16x16x32_bf16(kv0, qf[qn][0], s[qn][t], 0, 0, 0);
                    s[qn][t] = __builtin_amdgcn_mfma_f32_16x16x32_bf16(kv1, qf[qn][1], s[qn][t], 0, 0, 0);
                }
            }
            __builtin_amdgcn_s_setprio(0);

            if (j == jmine) {                     // diagonal tile: mask k > q
#pragma unroll
                for (int t = 0; t < 4; ++t) {
                    const int kb = j * 64 + t * 16 + quad * 4;
#pragma unroll
                    for (int r = 0; r < 4; ++r)
#pragma unroll
                        for (int qn = 0; qn < 4; ++qn)
                            if (kb + r > q0 + 16 * qn) s[qn][t][r] = -1e30f;
                }
            }

            // fixed-max softmax in exp2 domain; column sums in-reg + 2 shfl per qn
            float rs[4] = {0.f, 0.f, 0.f, 0.f};
#pragma unroll
            for (int qn = 0; qn < 4; ++qn)
#pragma unroll
                for (int t = 0; t < 4; ++t)
#pragma unroll
                    for (int r = 0; r < 4; ++r) {
                        const float p = __builtin_amdgcn_exp2f(s[qn][t][r]);
                        s[qn][t][r] = p;
                        rs[qn] += p;
                    }
#pragma unroll
            for (int qn = 0; qn < 4; ++qn) {
                rs[qn] += __shfl_xor(rs[qn], 16);
                rs[qn] += __shfl_xor(rs[qn], 32);
                l[qn] += rs[qn];
            }

            // pack P pairs (trunc bf16); own regs ARE the PV B-frag (k-permuted)
            union { int i[8]; s8 v[2]; } pk[4];
#pragma unroll
            for (int qn = 0; qn < 4; ++qn)
#pragma unroll
                for (int t = 0; t < 4; ++t) {
                    pk[qn].i[t * 2]     = pkbf(s[qn][t][1], s[qn][t][0]);
                    pk[qn].i[t * 2 + 1] = pkbf(s[qn][t][3], s[qn][t][2]);
                }

            // O^T[d][q] += V^T . P; one V fragment pair feeds 4 q-subtiles
            __builtin_amdgcn_s_setprio(1);
#pragma unroll
            for (int t = 0; t < 4; ++t) {
                const int rbase = (t * 16 + l16) * 64;
                s8 va0 = *(const s8*)&VsP[rbase + coff0];
                s8 va1 = *(const s8*)&VsP[rbase + coff1];
#pragma unroll
                for (int qn = 0; qn < 4; ++qn) {
                    o[qn][t] = __builtin_amdgcn_mfma_f32_16x16x32_bf16(va0, pk[qn].v[0], o[qn][t], 0, 0, 0);
                    o[qn][t] = __builtin_amdgcn_mfma_f32_16x16x32_bf16(va1, pk[qn].v[1], o[qn][t], 0, 0, 0);
                }
            }
            __builtin_amdgcn_s_setprio(0);
        }
    }
#undef STAGE_PAIR

    // ---- cross-parity merge via dead Ks/Vs, then store ----
    __syncthreads();                              // all LDS reads + staging quiesced
    float* mO = (float*)&Ks[0][0][0][0];          // 2 slots x 64 lanes x 256B = 32KB
    float* mL = (float*)&Vs[0][0][0][0];          // 2 slots x 64 lanes x 4f   =  2KB
    const int slot = isA ? 0 : 1;
    const int mrow = slot * 64 + lane;
    char* mp = (char*)mO + (size_t)mrow * 256;
    const int msw = (lane & 7) << 4;              // bank-spread XOR (bits 4-6, bijective)
    if (par == 1) {                               // park partials
#pragma unroll
        for (int qn = 0; qn < 4; ++qn) {
#pragma unroll
            for (int t = 0; t < 4; ++t)
                *(f4*)(mp + ((qn * 64 + t * 16) ^ msw)) = o[qn][t];
            mL[mrow * 4 + qn] = l[qn];
        }
    }
    __syncthreads();
    if (par == 0) {                               // merge + normalize + store 64 rows
#pragma unroll
        for (int qn = 0; qn < 4; ++qn) {
            const float lq  = l[qn] + mL[mrow * 4 + qn];
            const float inv = 1.0f / lq;
#pragma unroll
            for (int t = 0; t < 4; ++t) {
                f4 v = o[qn][t] + *(const f4*)(mp + ((qn * 64 + t * 16) ^ msw));
                us4 ov;
#pragma unroll
                for (int r = 0; r < 4; ++r) ov[r] = f2bf(v[r] * inv);
                *(us4*)&Og[(size_t)(q0 + 16 * qn) * EMB + colbase + t * 16 + quad * 4] = ov;
            }
        }
    }
}

extern "C" void kernel_launch(void* const* d_in, const int* in_sizes, int n_in,
                              void* d_out, int out_size, void* d_ws, size_t ws_size,
                              hipStream_t stream) {
    const float* x  = (const float*)d_in[0];
    const float* Wq = (const float*)d_in[1];
    const float* bq = (const float*)d_in[2];
    const float* Wk = (const float*)d_in[3];
    const float* bk = (const float*)d_in[4];
    const float* Wv = (const float*)d_in[5];
    const float* bv = (const float*)d_in[6];
    const float* Wo = (const float*)d_in[7];
    const float* bo = (const float*)d_in[8];
    float* out = (float*)d_out;

    unsigned short* ws = (unsigned short*)d_ws;
    unsigned short* xb  = ws;                          // [4096][1024]
    unsigned short* Wqb = xb  + (size_t)SEQ * EMB;     // [1024][1024] x4
    unsigned short* Wkb = Wqb + (size_t)EMB * EMB;
    unsigned short* Wvb = Wkb + (size_t)EMB * EMB;
    unsigned short* Wob = Wvb + (size_t)EMB * EMB;
    unsigned short* Qb  = Wob + (size_t)EMB * EMB;     // [4096][1024], pre-scaled 0.125*log2e
    unsigned short* Kb  = Qb  + (size_t)SEQ * EMB;     // [4096][1024]
    unsigned short* Vtb = Kb  + (size_t)SEQ * EMB;     // [1024][4096]  V^T, k-permuted cols
    unsigned short* Ab  = Vtb + (size_t)SEQ * EMB;     // attn out

    cvt_all<<<8192, 256, 0, stream>>>(x, Wq, Wk, Wv, Wo, xb, Wqb, Wkb, Wvb, Wob);

    // V region writes Vtb directly (transposed + k-permuted); no transpose kernel
    qkv_gemm<<<dim3(SEQ / 128, 24), 256, 0, stream>>>(xb, Wqb, Wkb, Wvb, bq, bk, bv, Qb, Kb, Vtb);

    attn_kernel<<<dim3(NH, 32), 256, 0, stream>>>(Qb, Kb, Vtb, Ab);

    gemm_op<<<dim3(SEQ / 128, EMB / 64), 256, 0, stream>>>(Ab, Wob, bo, out);
}